// Round 1
// baseline (403.845 us; speedup 1.0000x reference)
//
#include <hip/hip_runtime.h>

#define NM_ 1000000
#define NT_ 10000
#define NF_ 200000
#define N_TOTAL_ (NM_ + NT_ + NF_)
#define NBX_ 512
#define NBY_ 512
#define NBINS_ (NBX_ * NBY_)
#define BSX_ 2.0f
#define BSY_ 2.0f
#define K_MOV_ 5
#define K_FIX_ 10
#define TD_ 0.9f
#define BIN_AREA_ 4.0f
#define PAD_VAL_ (TD_ * BIN_AREA_)   // 3.6
#define SQRT2x2_ 2.8284271247461903f

__global__ void zero_kernel(float* __restrict__ dmap, float* __restrict__ out) {
    int i = blockIdx.x * blockDim.x + threadIdx.x;
    if (i < NBINS_) dmap[i] = 0.0f;
    if (i == 0) { out[0] = 0.0f; out[1] = 0.0f; }
}

// Terminals: indices [NM, NM+NT), weight = TARGET_DENSITY (folded 0.9), K=10,
// raw x,y,sx,sy (no clamping).
__global__ void splat_fix(const float* __restrict__ px, const float* __restrict__ py,
                          const float* __restrict__ sxp, const float* __restrict__ syp,
                          float* __restrict__ dmap) {
    int t = blockIdx.x * blockDim.x + threadIdx.x;
    if (t >= NT_) return;
    int i = NM_ + t;
    float x = px[i], y = py[i];
    float sx = sxp[i], sy = syp[i];
    int bx0 = (int)floorf(x * 0.5f);
    int by0 = (int)floorf(y * 0.5f);
    float ox[K_FIX_], oy[K_FIX_];
#pragma unroll
    for (int k = 0; k < K_FIX_; k++) {
        int bx = bx0 + k;
        float o = fminf(x + sx, (bx + 1) * BSX_) - fmaxf(x, bx * BSX_);
        ox[k] = (bx >= 0 && bx < NBX_) ? fmaxf(o, 0.0f) : 0.0f;
        int by = by0 + k;
        float o2 = fminf(y + sy, (by + 1) * BSY_) - fmaxf(y, by * BSY_);
        oy[k] = (by >= 0 && by < NBY_) ? fmaxf(o2, 0.0f) : 0.0f;
    }
#pragma unroll
    for (int kx = 0; kx < K_FIX_; kx++) {
        if (ox[kx] <= 0.0f) continue;
        int bx = bx0 + kx;
        float wox = TD_ * ox[kx];
#pragma unroll
        for (int ky = 0; ky < K_FIX_; ky++) {
            if (oy[ky] <= 0.0f) continue;
            int by = by0 + ky;
            atomicAdd(&dmap[bx * NBY_ + by], wox * oy[ky]);
        }
    }
}

// Movable + fillers: all i except [NM, NM+NT). Clamped sizes, centered offset,
// ratio weight, K=5.
__global__ void splat_mov(const float* __restrict__ px, const float* __restrict__ py,
                          const float* __restrict__ sxp, const float* __restrict__ syp,
                          float* __restrict__ dmap) {
    int i = blockIdx.x * blockDim.x + threadIdx.x;
    if (i >= N_TOTAL_) return;
    if (i >= NM_ && i < NM_ + NT_) return;
    float sx = sxp[i], sy = syp[i];
    float sxc = fmaxf(sx, SQRT2x2_);
    float syc = fmaxf(sy, SQRT2x2_);
    float x = px[i] + (sx - sxc) * 0.5f;
    float y = py[i] + (sy - syc) * 0.5f;
    float w = (sx * sy) / (sxc * syc);
    int bx0 = (int)floorf(x * 0.5f);
    int by0 = (int)floorf(y * 0.5f);
    float ox[K_MOV_], oy[K_MOV_];
#pragma unroll
    for (int k = 0; k < K_MOV_; k++) {
        int bx = bx0 + k;
        float o = fminf(x + sxc, (bx + 1) * BSX_) - fmaxf(x, bx * BSX_);
        ox[k] = (bx >= 0 && bx < NBX_) ? fmaxf(o, 0.0f) : 0.0f;
        int by = by0 + k;
        float o2 = fminf(y + syc, (by + 1) * BSY_) - fmaxf(y, by * BSY_);
        oy[k] = (by >= 0 && by < NBY_) ? fmaxf(o2, 0.0f) : 0.0f;
    }
#pragma unroll
    for (int kx = 0; kx < K_MOV_; kx++) {
        if (ox[kx] <= 0.0f) continue;
        int bx = bx0 + kx;
        float wox = w * ox[kx];
#pragma unroll
        for (int ky = 0; ky < K_MOV_; ky++) {
            if (oy[ky] <= 0.0f) continue;
            int by = by0 + ky;
            atomicAdd(&dmap[bx * NBY_ + by], wox * oy[ky]);
        }
    }
}

__global__ void reduce_kernel(const float* __restrict__ dmap, float* __restrict__ out) {
    float sum = 0.0f, mx = 0.0f;
    for (int i = blockIdx.x * blockDim.x + threadIdx.x; i < NBINS_;
         i += gridDim.x * blockDim.x) {
        int ix = i >> 9;        // NBY = 512
        int iy = i & (NBY_ - 1);
        float v = dmap[i];
        bool pad = (ix < 1) | (ix >= NBX_ - 1) | (iy < 1) | (iy >= NBY_ - 1);
        if (pad) v = PAD_VAL_;
        sum += fmaxf(v - PAD_VAL_, 0.0f);
        mx = fmaxf(mx, v);
    }
    // wave64 reduce
#pragma unroll
    for (int off = 32; off > 0; off >>= 1) {
        sum += __shfl_down(sum, off);
        mx = fmaxf(mx, __shfl_down(mx, off));
    }
    __shared__ float ssum[8], smx[8];
    int lane = threadIdx.x & 63;
    int wid = threadIdx.x >> 6;
    if (lane == 0) { ssum[wid] = sum; smx[wid] = mx; }
    __syncthreads();
    if (threadIdx.x == 0) {
        int nw = blockDim.x >> 6;
        float s = 0.0f, m = 0.0f;
        for (int w = 0; w < nw; w++) { s += ssum[w]; m = fmaxf(m, smx[w]); }
        atomicAdd(&out[0], s);
        // max_density = max(dmap)/bin_area; values are all >= 0 so uint-bits
        // compare == float compare, and *0.25 preserves order.
        atomicMax((unsigned int*)&out[1], __float_as_uint(m * 0.25f));
    }
}

extern "C" void kernel_launch(void* const* d_in, const int* in_sizes, int n_in,
                              void* d_out, int out_size, void* d_ws, size_t ws_size,
                              hipStream_t stream) {
    const float* pos = (const float*)d_in[0];
    const float* nsx = (const float*)d_in[1];
    const float* nsy = (const float*)d_in[2];
    const float* px = pos;
    const float* py = pos + N_TOTAL_;
    float* out = (float*)d_out;
    float* dmap = (float*)d_ws;   // NBINS_ floats = 1 MiB

    zero_kernel<<<(NBINS_ + 255) / 256, 256, 0, stream>>>(dmap, out);
    splat_fix<<<(NT_ + 255) / 256, 256, 0, stream>>>(px, py, nsx, nsy, dmap);
    splat_mov<<<(N_TOTAL_ + 255) / 256, 256, 0, stream>>>(px, py, nsx, nsy, dmap);
    reduce_kernel<<<1024, 256, 0, stream>>>(dmap, out);
}

// Round 2
// 151.938 us; speedup vs baseline: 2.6580x; 2.6580x over previous
//
#include <hip/hip_runtime.h>

#define NM_ 1000000
#define NT_ 10000
#define NF_ 200000
#define N_TOTAL_ 1210000
#define NBX_ 512
#define NBY_ 512
#define NBINS_ (NBX_ * NBY_)
#define TD_ 0.9f
#define BIN_AREA_ 4.0f
#define PAD_VAL_ 3.6f
#define SQRT2x2_ 2.8284271247461903f

// tiling for the sort+LDS-privatized splat
#define TSZ_ 16                 // bins per tile side
#define TSH_ 4
#define TGX_ 32                 // tiles per axis
#define NTILES_ 1024
#define HALO_ 2                 // movable footprint spans <= 2 extra bins
#define TW_ 18                  // TSZ_ + HALO_
#define TAREA_ (TW_ * TW_)      // 324
#define NB_ 256                 // blocks in count/scatter passes
#define CHUNK_ ((N_TOTAL_ + NB_ - 1) / NB_)   // 4727
#define NRECMAX_ (N_TOTAL_ + 4 * NT_)         // terminals duplicated into <=4 tiles

static __device__ __forceinline__ int imin_(int a, int b) { return a < b ? a : b; }
static __device__ __forceinline__ int imax_(int a, int b) { return a > b ? a : b; }

// Per-cell geometry, identical fp sequence in count & scatter passes.
__device__ __forceinline__ void cell_params(int i,
        const float* __restrict__ px, const float* __restrict__ py,
        const float* __restrict__ sxp, const float* __restrict__ syp,
        float& x, float& y, float& sx, float& sy, float& w, bool& fix) {
    float sx0 = sxp[i], sy0 = syp[i];
    fix = (i >= NM_) && (i < NM_ + NT_);
    if (fix) {
        x = px[i]; y = py[i]; sx = sx0; sy = sy0; w = TD_;
    } else {
        float sxc = fmaxf(sx0, SQRT2x2_);
        float syc = fmaxf(sy0, SQRT2x2_);
        x = px[i] + (sx0 - sxc) * 0.5f;
        y = py[i] + (sy0 - syc) * 0.5f;
        sx = sxc; sy = syc;
        w = (sx0 * sy0) / (sxc * syc);
    }
}

// ---------------- pass 1: per-(block,tile) counts ----------------
__global__ void count_kernel(const float* __restrict__ px, const float* __restrict__ py,
                             const float* __restrict__ sxp, const float* __restrict__ syp,
                             int* __restrict__ cnt) {
    __shared__ int hist[NTILES_];
    for (int t = threadIdx.x; t < NTILES_; t += blockDim.x) hist[t] = 0;
    __syncthreads();
    int b = blockIdx.x;
    int lo = b * CHUNK_, hi = imin_(lo + CHUNK_, N_TOTAL_);
    for (int i = lo + threadIdx.x; i < hi; i += blockDim.x) {
        float x, y, sx, sy, w; bool fix;
        cell_params(i, px, py, sxp, syp, x, y, sx, sy, w, fix);
        int bx0 = (int)floorf(x * 0.5f);
        int by0 = (int)floorf(y * 0.5f);
        if (!fix) {
            int tx = imax_(bx0, 0) >> TSH_, ty = imax_(by0, 0) >> TSH_;
            atomicAdd(&hist[tx * TGX_ + ty], 1);
        } else {
            int bxm = imin_((int)floorf((x + sx) * 0.5f), NBX_ - 1);
            int bym = imin_((int)floorf((y + sy) * 0.5f), NBY_ - 1);
            int txA = bx0 >> TSH_, txB = bxm >> TSH_;
            int tyA = by0 >> TSH_, tyB = bym >> TSH_;
            for (int tx = txA; tx <= txB; tx++)
                for (int ty = tyA; ty <= tyB; ty++)
                    atomicAdd(&hist[tx * TGX_ + ty], 1);
        }
    }
    __syncthreads();
    for (int t = threadIdx.x; t < NTILES_; t += blockDim.x)
        cnt[b * NTILES_ + t] = hist[t];
}

// ---------------- pass 2: prefix scan over (tile, block) ----------------
__global__ void scan_kernel(const int* __restrict__ cnt, int* __restrict__ start,
                            int* __restrict__ aux, float* __restrict__ out) {
    int t = threadIdx.x;                 // 1024 threads, one per tile
    int s = 0;
    for (int b = 0; b < NB_; b++) s += cnt[b * NTILES_ + t];
    int lane = t & 63, wv = t >> 6;
    int incl = s;
#pragma unroll
    for (int off = 1; off < 64; off <<= 1) {
        int n = __shfl_up(incl, off);
        if (lane >= off) incl += n;
    }
    __shared__ int wtot[16], wbase[16];
    if (lane == 63) wtot[wv] = incl;
    __syncthreads();
    if (t == 0) {
        int a = 0;
        for (int k = 0; k < 16; k++) { wbase[k] = a; a += wtot[k]; }
        aux[0] = a;                      // total record count
        out[0] = 0.0f; out[1] = 0.0f;    // zero outputs every call
    }
    __syncthreads();
    int run = wbase[wv] + (incl - s);    // exclusive prefix across tiles
    for (int b = 0; b < NB_; b++) {
        start[b * NTILES_ + t] = run;
        run += cnt[b * NTILES_ + t];
    }
}

// ---------------- pass 3: scatter records ----------------
__global__ void scatter_kernel(const float* __restrict__ px, const float* __restrict__ py,
                               const float* __restrict__ sxp, const float* __restrict__ syp,
                               const int* __restrict__ start,
                               float4* __restrict__ rec, float* __restrict__ wrec) {
    __shared__ int cur[NTILES_];
    int b = blockIdx.x;
    for (int t = threadIdx.x; t < NTILES_; t += blockDim.x)
        cur[t] = start[b * NTILES_ + t];
    __syncthreads();
    int lo = b * CHUNK_, hi = imin_(lo + CHUNK_, N_TOTAL_);
    for (int i = lo + threadIdx.x; i < hi; i += blockDim.x) {
        float x, y, sx, sy, w; bool fix;
        cell_params(i, px, py, sxp, syp, x, y, sx, sy, w, fix);
        int bx0 = (int)floorf(x * 0.5f);
        int by0 = (int)floorf(y * 0.5f);
        if (!fix) {
            int t = (imax_(bx0, 0) >> TSH_) * TGX_ + (imax_(by0, 0) >> TSH_);
            int slot = atomicAdd(&cur[t], 1);
            rec[slot] = make_float4(x, y, sx, sy);
            wrec[slot] = w;
        } else {
            int bxm = imin_((int)floorf((x + sx) * 0.5f), NBX_ - 1);
            int bym = imin_((int)floorf((y + sy) * 0.5f), NBY_ - 1);
            int txA = bx0 >> TSH_, txB = bxm >> TSH_;
            int tyA = by0 >> TSH_, tyB = bym >> TSH_;
            for (int tx = txA; tx <= txB; tx++)
                for (int ty = tyA; ty <= tyB; ty++) {
                    int slot = atomicAdd(&cur[tx * TGX_ + ty], 1);
                    rec[slot] = make_float4(x, y, sx, sy);
                    wrec[slot] = -w;     // sign flags terminal: interior-only clip
                }
        }
    }
}

// ---------------- pass 4: per-tile LDS accumulate ----------------
__global__ void accum_kernel(const float4* __restrict__ rec, const float* __restrict__ wrec,
                             const int* __restrict__ start, const int* __restrict__ aux,
                             float* __restrict__ tiles) {
    __shared__ float m[TAREA_];
    int tile = blockIdx.x;
    int tx = tile >> 5, ty = tile & (TGX_ - 1);
    for (int k = threadIdx.x; k < TAREA_; k += blockDim.x) m[k] = 0.0f;
    __syncthreads();
    int s = start[tile];                                  // b=0 row == tile base
    int e = (tile < NTILES_ - 1) ? start[tile + 1] : aux[0];
    int tx16 = tx << TSH_, ty16 = ty << TSH_;
    for (int i = s + threadIdx.x; i < e; i += blockDim.x) {
        float4 r = rec[i];
        float w = wrec[i];
        bool fix = (w < 0.0f);
        float wa = fabsf(w);
        int cap = fix ? (TSZ_ - 1) : (TW_ - 1);           // terminals: interior only
        int bx0 = (int)floorf(r.x * 0.5f);
        int by0 = (int)floorf(r.y * 0.5f);
        int bxA = imax_(bx0, tx16), byA = imax_(by0, ty16);
        int bxB = imin_(imin_((int)floorf((r.x + r.z) * 0.5f), tx16 + cap), NBX_ - 1);
        int byB = imin_(imin_((int)floorf((r.y + r.w) * 0.5f), ty16 + cap), NBY_ - 1);
        for (int bx = bxA; bx <= bxB; bx++) {
            float ox = fminf(r.x + r.z, (bx + 1) * 2.0f) - fmaxf(r.x, bx * 2.0f);
            ox = fmaxf(ox, 0.0f) * wa;
            for (int by = byA; by <= byB; by++) {
                float oy = fminf(r.y + r.w, (by + 1) * 2.0f) - fmaxf(r.y, by * 2.0f);
                oy = fmaxf(oy, 0.0f);
                atomicAdd(&m[(bx - tx16) * TW_ + (by - ty16)], ox * oy);
            }
        }
    }
    __syncthreads();
    for (int k = threadIdx.x; k < TAREA_; k += blockDim.x)
        tiles[tile * TAREA_ + k] = m[k];
}

// ---------------- pass 5: gather + reduce ----------------
__global__ void reduce2_kernel(const float* __restrict__ tiles, float* __restrict__ out) {
    float sum = 0.0f, mx = 0.0f;
    for (int i = blockIdx.x * blockDim.x + threadIdx.x; i < NBINS_;
         i += gridDim.x * blockDim.x) {
        int gx = i >> 9, gy = i & (NBY_ - 1);
        float v;
        bool pad = (gx < 1) | (gx >= NBX_ - 1) | (gy < 1) | (gy >= NBY_ - 1);
        if (pad) {
            v = PAD_VAL_;
        } else {
            int tx = gx >> TSH_, lx = gx & (TSZ_ - 1);
            int ty = gy >> TSH_, ly = gy & (TSZ_ - 1);
            v = tiles[(tx * TGX_ + ty) * TAREA_ + lx * TW_ + ly];
            if (lx < HALO_ && tx > 0)
                v += tiles[((tx - 1) * TGX_ + ty) * TAREA_ + (lx + TSZ_) * TW_ + ly];
            if (ly < HALO_ && ty > 0)
                v += tiles[(tx * TGX_ + (ty - 1)) * TAREA_ + lx * TW_ + (ly + TSZ_)];
            if (lx < HALO_ && ly < HALO_ && tx > 0 && ty > 0)
                v += tiles[((tx - 1) * TGX_ + (ty - 1)) * TAREA_ + (lx + TSZ_) * TW_ + (ly + TSZ_)];
        }
        sum += fmaxf(v - PAD_VAL_, 0.0f);
        mx = fmaxf(mx, v);
    }
#pragma unroll
    for (int off = 32; off > 0; off >>= 1) {
        sum += __shfl_down(sum, off);
        mx = fmaxf(mx, __shfl_down(mx, off));
    }
    __shared__ float ssum[8], smx[8];
    int lane = threadIdx.x & 63, wid = threadIdx.x >> 6;
    if (lane == 0) { ssum[wid] = sum; smx[wid] = mx; }
    __syncthreads();
    if (threadIdx.x == 0) {
        int nw = blockDim.x >> 6;
        float s = 0.0f, m = 0.0f;
        for (int w = 0; w < nw; w++) { s += ssum[w]; m = fmaxf(m, smx[w]); }
        atomicAdd(&out[0], s);
        atomicMax((unsigned int*)&out[1], __float_as_uint(m * 0.25f));
    }
}

// ================= legacy fallback (round-1 path) =================
__global__ void zero_kernel(float* __restrict__ dmap, float* __restrict__ out) {
    int i = blockIdx.x * blockDim.x + threadIdx.x;
    if (i < NBINS_) dmap[i] = 0.0f;
    if (i == 0) { out[0] = 0.0f; out[1] = 0.0f; }
}

__global__ void splat_fix(const float* __restrict__ px, const float* __restrict__ py,
                          const float* __restrict__ sxp, const float* __restrict__ syp,
                          float* __restrict__ dmap) {
    int t = blockIdx.x * blockDim.x + threadIdx.x;
    if (t >= NT_) return;
    int i = NM_ + t;
    float x = px[i], y = py[i], sx = sxp[i], sy = syp[i];
    int bx0 = (int)floorf(x * 0.5f), by0 = (int)floorf(y * 0.5f);
    for (int kx = 0; kx < 10; kx++) {
        int bx = bx0 + kx;
        if (bx < 0 || bx >= NBX_) continue;
        float ox = fminf(x + sx, (bx + 1) * 2.0f) - fmaxf(x, bx * 2.0f);
        if (ox <= 0.0f) continue;
        for (int ky = 0; ky < 10; ky++) {
            int by = by0 + ky;
            if (by < 0 || by >= NBY_) continue;
            float oy = fminf(y + sy, (by + 1) * 2.0f) - fmaxf(y, by * 2.0f);
            if (oy <= 0.0f) continue;
            atomicAdd(&dmap[bx * NBY_ + by], TD_ * ox * oy);
        }
    }
}

__global__ void splat_mov(const float* __restrict__ px, const float* __restrict__ py,
                          const float* __restrict__ sxp, const float* __restrict__ syp,
                          float* __restrict__ dmap) {
    int i = blockIdx.x * blockDim.x + threadIdx.x;
    if (i >= N_TOTAL_) return;
    if (i >= NM_ && i < NM_ + NT_) return;
    float sx = sxp[i], sy = syp[i];
    float sxc = fmaxf(sx, SQRT2x2_), syc = fmaxf(sy, SQRT2x2_);
    float x = px[i] + (sx - sxc) * 0.5f, y = py[i] + (sy - syc) * 0.5f;
    float w = (sx * sy) / (sxc * syc);
    int bx0 = (int)floorf(x * 0.5f), by0 = (int)floorf(y * 0.5f);
    for (int kx = 0; kx < 5; kx++) {
        int bx = bx0 + kx;
        if (bx < 0 || bx >= NBX_) continue;
        float ox = fminf(x + sxc, (bx + 1) * 2.0f) - fmaxf(x, bx * 2.0f);
        if (ox <= 0.0f) continue;
        for (int ky = 0; ky < 5; ky++) {
            int by = by0 + ky;
            if (by < 0 || by >= NBY_) continue;
            float oy = fminf(y + syc, (by + 1) * 2.0f) - fmaxf(y, by * 2.0f);
            if (oy <= 0.0f) continue;
            atomicAdd(&dmap[bx * NBY_ + by], w * ox * oy);
        }
    }
}

__global__ void reduce_kernel(const float* __restrict__ dmap, float* __restrict__ out) {
    float sum = 0.0f, mx = 0.0f;
    for (int i = blockIdx.x * blockDim.x + threadIdx.x; i < NBINS_;
         i += gridDim.x * blockDim.x) {
        int ix = i >> 9, iy = i & (NBY_ - 1);
        float v = dmap[i];
        bool pad = (ix < 1) | (ix >= NBX_ - 1) | (iy < 1) | (iy >= NBY_ - 1);
        if (pad) v = PAD_VAL_;
        sum += fmaxf(v - PAD_VAL_, 0.0f);
        mx = fmaxf(mx, v);
    }
#pragma unroll
    for (int off = 32; off > 0; off >>= 1) {
        sum += __shfl_down(sum, off);
        mx = fmaxf(mx, __shfl_down(mx, off));
    }
    __shared__ float ssum[8], smx[8];
    int lane = threadIdx.x & 63, wid = threadIdx.x >> 6;
    if (lane == 0) { ssum[wid] = sum; smx[wid] = mx; }
    __syncthreads();
    if (threadIdx.x == 0) {
        int nw = blockDim.x >> 6;
        float s = 0.0f, m = 0.0f;
        for (int w = 0; w < nw; w++) { s += ssum[w]; m = fmaxf(m, smx[w]); }
        atomicAdd(&out[0], s);
        atomicMax((unsigned int*)&out[1], __float_as_uint(m * 0.25f));
    }
}

extern "C" void kernel_launch(void* const* d_in, const int* in_sizes, int n_in,
                              void* d_out, int out_size, void* d_ws, size_t ws_size,
                              hipStream_t stream) {
    const float* pos = (const float*)d_in[0];
    const float* nsx = (const float*)d_in[1];
    const float* nsy = (const float*)d_in[2];
    const float* px = pos;
    const float* py = pos + N_TOTAL_;
    float* out = (float*)d_out;

    size_t o_cnt   = 0;
    size_t o_start = o_cnt + (size_t)NB_ * NTILES_ * 4;
    size_t o_rec   = o_start + (size_t)NB_ * NTILES_ * 4;
    size_t o_w     = o_rec + (size_t)NRECMAX_ * 16;
    size_t o_tiles = o_w + (size_t)NRECMAX_ * 4;
    size_t o_aux   = o_tiles + (size_t)NTILES_ * TAREA_ * 4;
    size_t req     = o_aux + 16;

    if (ws_size >= req) {
        char* ws = (char*)d_ws;
        int*    cnt   = (int*)(ws + o_cnt);
        int*    start = (int*)(ws + o_start);
        float4* rec   = (float4*)(ws + o_rec);
        float*  wrec  = (float*)(ws + o_w);
        float*  tiles = (float*)(ws + o_tiles);
        int*    aux   = (int*)(ws + o_aux);

        count_kernel<<<NB_, 256, 0, stream>>>(px, py, nsx, nsy, cnt);
        scan_kernel<<<1, 1024, 0, stream>>>(cnt, start, aux, out);
        scatter_kernel<<<NB_, 256, 0, stream>>>(px, py, nsx, nsy, start, rec, wrec);
        accum_kernel<<<NTILES_, 256, 0, stream>>>(rec, wrec, start, aux, tiles);
        reduce2_kernel<<<1024, 256, 0, stream>>>(tiles, out);
    } else {
        float* dmap = (float*)d_ws;
        zero_kernel<<<(NBINS_ + 255) / 256, 256, 0, stream>>>(dmap, out);
        splat_fix<<<(NT_ + 255) / 256, 256, 0, stream>>>(px, py, nsx, nsy, dmap);
        splat_mov<<<(N_TOTAL_ + 255) / 256, 256, 0, stream>>>(px, py, nsx, nsy, dmap);
        reduce_kernel<<<1024, 256, 0, stream>>>(dmap, out);
    }
}